// Round 8
// baseline (166.566 us; speedup 1.0000x reference)
//
#include <hip/hip_runtime.h>

#define NN 256
#define HH 512
#define BB 128
#define PKS (5 * HH)   // floats per packed step row-set (w2m, w2a, w0, w1a, w1b)

typedef float f32x4 __attribute__((ext_vector_type(4)));
typedef __attribute__((address_space(3))) float       lds_f;
typedef __attribute__((address_space(3))) void        lds_v;
typedef __attribute__((address_space(1))) const void  glb_v;

// ---------------- prep: packed masked/transposed rows, one row-set per step -
// pk[i][0][k] = (k%255 <  i)           ? w2[i][k]     (mu row)
// pk[i][1][k] = (k%255 <  i)           ? w2[256+i][k] (alpha row)
// pk[i][2][k] = (k%255 >= i)           ? w0[k][i]     (w0 column i)
// pk[i][3][k] = (k%255 >= i%255)       ? w1[k][i]     (w1 column i)
// pk[i][4][k] = (k%255 >= (i+255)%255) ? w1[k][i+255]
__global__ __launch_bounds__(512)
void made_prep(const float* __restrict__ w0,
               const float* __restrict__ w1,
               const float* __restrict__ w2,
               float* __restrict__ pk) {
    const int i = blockIdx.x;     // step 0..255
    const int k = threadIdx.x;    // unit 0..511
    const int lev = k % 255;
    float* row = pk + (size_t)i * PKS;
    row[k]          = (lev < i)  ? w2[i * HH + k]        : 0.f;
    row[HH + k]     = (lev < i)  ? w2[(NN + i) * HH + k] : 0.f;
    row[2*HH + k]   = (lev >= i) ? w0[k * NN + i]        : 0.f;
    const int l1 = i % 255;
    row[3*HH + k]   = (lev >= l1) ? w1[k * HH + i]       : 0.f;
    const int j2 = i + 255;
    const int l2 = j2 % 255;
    row[4*HH + k]   = (lev >= l2) ? w1[k * HH + j2]      : 0.f;
}

// ---------------- single-wave sequential kernel -----------------------------
__device__ __forceinline__ float rl_f(float v, int lane) {
    return __int_as_float(__builtin_amdgcn_readlane(__float_as_int(v), lane));
}

__device__ __forceinline__ f32x4 ld4(const float* p) { return *(const f32x4*)p; }

// async global -> LDS DMA, 16B per lane (dest = uniform LDS base + lane*16)
__device__ __forceinline__ void gld16(const float* g, float* l) {
    __builtin_amdgcn_global_load_lds((glb_v*)g, (lds_v*)l, 16, 0, 0);
}

#define DPP_ADD(v, ctrl, rm) \
    ((v) + __int_as_float(__builtin_amdgcn_update_dpp(0, __float_as_int(v), (ctrl), (rm), 0xf, false)))

// full-wave (64-lane) sum of pm and pa; totals end up in lane 63
__device__ __forceinline__ void reduce2(float& pm, float& pa) {
    pm = DPP_ADD(pm, 0x111, 0xf);  pa = DPP_ADD(pa, 0x111, 0xf);  // row_shr:1
    pm = DPP_ADD(pm, 0x112, 0xf);  pa = DPP_ADD(pa, 0x112, 0xf);  // row_shr:2
    pm = DPP_ADD(pm, 0x114, 0xf);  pa = DPP_ADD(pa, 0x114, 0xf);  // row_shr:4
    pm = DPP_ADD(pm, 0x118, 0xf);  pa = DPP_ADD(pa, 0x118, 0xf);  // row_shr:8
    pm = DPP_ADD(pm, 0x142, 0xa);  pa = DPP_ADD(pa, 0x142, 0xa);  // row_bcast15
    pm = DPP_ADD(pm, 0x143, 0xc);  pa = DPP_ADD(pa, 0x143, 0xc);  // row_bcast31
}

// 10 ds_read_b128 of one slot. No internal waits — the caller does a full
// lgkmcnt(0) + sched_barrier(0) before any use (rule-#18 pattern).
// Lane t reads bytes [16t,16t+16) of each 1KB half-row: contiguous per lane.
#define LDS_READ10(VA)                                                       \
    asm volatile(                                                            \
        "ds_read_b128 %0, %10 offset:0\n\t"                                  \
        "ds_read_b128 %1, %10 offset:1024\n\t"                               \
        "ds_read_b128 %2, %10 offset:2048\n\t"                               \
        "ds_read_b128 %3, %10 offset:3072\n\t"                               \
        "ds_read_b128 %4, %10 offset:4096\n\t"                               \
        "ds_read_b128 %5, %10 offset:5120\n\t"                               \
        "ds_read_b128 %6, %10 offset:6144\n\t"                               \
        "ds_read_b128 %7, %10 offset:7168\n\t"                               \
        "ds_read_b128 %8, %10 offset:8192\n\t"                               \
        "ds_read_b128 %9, %10 offset:9216"                                   \
        : "=&v"(qA0), "=&v"(qA1), "=&v"(qB0), "=&v"(qB1), "=&v"(qC0),        \
          "=&v"(qC1), "=&v"(qD0), "=&v"(qD1), "=&v"(qE0), "=&v"(qE1)         \
        : "v"(VA))

// One autoregressive step. r is a LITERAL 0..7; g is the (uniform) loop var.
// Lane t owns units {4t..4t+3} (lo) and {256+4t..256+4t+3} (hi).
// Total-order pipeline: vmcnt(0) -> ds_read slot i&3 -> lgkmcnt(0) ->
// refill DMA into DISJOINT slot (i+3)&3 -> compute.
#define STEP(g, r) do {                                                      \
    const int i_ = ((g) << 3) | (r);                                         \
    asm volatile("s_waitcnt vmcnt(0)" ::: "memory");   /* all LDS wr done */ \
    __builtin_amdgcn_sched_barrier(0);                                       \
    f32x4 qA0, qA1, qB0, qB1, qC0, qC1, qD0, qD1, qE0, qE1;                  \
    const unsigned va_ = ((r)&3)==0 ? va0 : ((r)&3)==1 ? va1                 \
                       : ((r)&3)==2 ? va2 : va3;                             \
    LDS_READ10(va_);                                                         \
    asm volatile("s_waitcnt lgkmcnt(0)" ::: "memory");                       \
    __builtin_amdgcn_sched_barrier(0);                                       \
    /* refill slot consumed LAST step (disjoint from the one just read);     \
       its previous reads completed at the previous step's lgkmcnt(0) */     \
    {                                                                        \
        const float* gs_ = pk + (size_t)((i_ + 3) & 255) * PKS + 4 * t;      \
        float* ls_ = lds4 + (((r) + 3) & 3) * 2560;                          \
        gld16(gs_,        ls_       ); gld16(gs_ + 256,  ls_ + 256 );        \
        gld16(gs_ + 512,  ls_ + 512 ); gld16(gs_ + 768,  ls_ + 768 );        \
        gld16(gs_ + 1024, ls_ + 1024); gld16(gs_ + 1280, ls_ + 1280);        \
        gld16(gs_ + 1536, ls_ + 1536); gld16(gs_ + 1792, ls_ + 1792);        \
        gld16(gs_ + 2048, ls_ + 2048); gld16(gs_ + 2304, ls_ + 2304);        \
    }                                                                        \
    __builtin_amdgcn_sched_barrier(0);                                       \
    /* dots over the 8 owned units */                                        \
    float h0_=fmaxf(a1lo[0],0.f), h1_=fmaxf(a1lo[1],0.f);                    \
    float h2_=fmaxf(a1lo[2],0.f), h3_=fmaxf(a1lo[3],0.f);                    \
    float h4_=fmaxf(a1hi[0],0.f), h5_=fmaxf(a1hi[1],0.f);                    \
    float h6_=fmaxf(a1hi[2],0.f), h7_=fmaxf(a1hi[3],0.f);                    \
    float pm_ = (fmaf(h1_,qA0[1],h0_*qA0[0]) + fmaf(h3_,qA0[3],h2_*qA0[2]))  \
              + (fmaf(h5_,qA1[1],h4_*qA1[0]) + fmaf(h7_,qA1[3],h6_*qA1[2])); \
    float pa_ = (fmaf(h1_,qB0[1],h0_*qB0[0]) + fmaf(h3_,qB0[3],h2_*qB0[2]))  \
              + (fmaf(h5_,qB1[1],h4_*qB1[0]) + fmaf(h7_,qB1[3],h6_*qB1[2])); \
    reduce2(pm_, pa_);                                                       \
    const int Li_ = 2*(g) + ((r)>>2);                                        \
    float tm_ = rl_f(pm_, 63), ta_ = rl_f(pa_, 63);                          \
    float mu_ = tm_ + rl_f(b2lo[(r)&3], Li_);                                \
    float al_ = ta_ + rl_f(b2hi[(r)&3], Li_);                                \
    ldacc += al_;                                                            \
    float zi_ = rl_f(zrv[(r)&3], Li_);                                       \
    float xi_ = fmaf(zi_, __expf(al_), mu_);                                 \
    xo[(r)&3] = (t == Li_) ? xi_ : xo[(r)&3];                                \
    /* publish A: unit i (lo half, lane Li_, slot r&3) */                    \
    float a0A_ = rl_f(a0lo[(r)&3], Li_);                                     \
    float w0A_ = rl_f(qC0[(r)&3], Li_);                                      \
    float a0B_, w0B_;                                                        \
    if ((r) == 0) {   /* unit 255+i: i==0 -> unit 255 (lo, lane63 slot3) */  \
        const int lbn_ = 2*(g) - 1;                                          \
        float aB0_ = rl_f(a0lo[3], 63), wB0_ = rl_f(qC0[3], 63);             \
        float aBn_ = rl_f(a0hi[3], lbn_), wBn_ = rl_f(qC1[3], lbn_);         \
        a0B_ = ((g) == 0) ? aB0_ : aBn_;                                     \
        w0B_ = ((g) == 0) ? wB0_ : wBn_;                                     \
    } else {          /* unit 256+(i-1): hi half */                          \
        const int lb_ = 2*(g) + (((r)-1)>>2);                                \
        a0B_ = rl_f(a0hi[((r)-1)&3], lb_);                                   \
        w0B_ = rl_f(qC1[((r)-1)&3], lb_);                                    \
    }                                                                        \
    float h0a_ = fmaxf(fmaf(xi_, w0A_, a0A_), 0.f);                          \
    float h0b_ = fmaxf(fmaf(xi_, w0B_, a0B_), 0.f);                          \
    if ((r) < 2) {    /* units 510/511 finalize at i=0,1 (hi, lane 63) */    \
        if ((g) == 0) {                                                      \
            float a0C_ = ((r)==0) ? rl_f(a0hi[2],63) : rl_f(a0hi[3],63);     \
            float w0C_ = ((r)==0) ? rl_f(qC1[2],63) : rl_f(qC1[3],63);       \
            float h0c_ = fmaxf(fmaf(xi_, w0C_, a0C_), 0.f);                  \
            f32x4 wl_ = ((r)==0) ? w1cAlo : w1cBlo;                          \
            f32x4 wh_ = ((r)==0) ? w1cAhi : w1cBhi;                          \
            a1lo[0]=fmaf(h0c_,wl_[0],a1lo[0]); a1lo[1]=fmaf(h0c_,wl_[1],a1lo[1]); \
            a1lo[2]=fmaf(h0c_,wl_[2],a1lo[2]); a1lo[3]=fmaf(h0c_,wl_[3],a1lo[3]); \
            a1hi[0]=fmaf(h0c_,wh_[0],a1hi[0]); a1hi[1]=fmaf(h0c_,wh_[1],a1hi[1]); \
            a1hi[2]=fmaf(h0c_,wh_[2],a1hi[2]); a1hi[3]=fmaf(h0c_,wh_[3],a1hi[3]); \
        }                                                                    \
    }                                                                        \
    a0lo[0]=fmaf(xi_,qC0[0],a0lo[0]); a0lo[1]=fmaf(xi_,qC0[1],a0lo[1]);      \
    a0lo[2]=fmaf(xi_,qC0[2],a0lo[2]); a0lo[3]=fmaf(xi_,qC0[3],a0lo[3]);      \
    a0hi[0]=fmaf(xi_,qC1[0],a0hi[0]); a0hi[1]=fmaf(xi_,qC1[1],a0hi[1]);      \
    a0hi[2]=fmaf(xi_,qC1[2],a0hi[2]); a0hi[3]=fmaf(xi_,qC1[3],a0hi[3]);      \
    a1lo[0]=fmaf(h0b_,qE0[0],fmaf(h0a_,qD0[0],a1lo[0]));                     \
    a1lo[1]=fmaf(h0b_,qE0[1],fmaf(h0a_,qD0[1],a1lo[1]));                     \
    a1lo[2]=fmaf(h0b_,qE0[2],fmaf(h0a_,qD0[2],a1lo[2]));                     \
    a1lo[3]=fmaf(h0b_,qE0[3],fmaf(h0a_,qD0[3],a1lo[3]));                     \
    a1hi[0]=fmaf(h0b_,qE1[0],fmaf(h0a_,qD1[0],a1hi[0]));                     \
    a1hi[1]=fmaf(h0b_,qE1[1],fmaf(h0a_,qD1[1],a1hi[1]));                     \
    a1hi[2]=fmaf(h0b_,qE1[2],fmaf(h0a_,qD1[2],a1hi[2]));                     \
    a1hi[3]=fmaf(h0b_,qE1[3],fmaf(h0a_,qD1[3],a1hi[3]));                     \
} while (0)

// One 64-thread wave per batch element. Weight stream pipelined through
// 4 LDS slots via global_load_lds DMA; FULL-DRAIN waits only (no counting).
__global__ __launch_bounds__(64, 1)
void made_seq64(const float* __restrict__ z,
                const float* __restrict__ b0g,
                const float* __restrict__ b1g,
                const float* __restrict__ b2g,
                const float* __restrict__ w1,
                const float* __restrict__ pk,
                float* __restrict__ out) {
    __shared__ float lds4[4 * 2560];          // 4 slots x 10 KiB
    const int bb = blockIdx.x;
    const int t  = threadIdx.x;

    f32x4 a0lo = ld4(b0g + 4*t), a0hi = ld4(b0g + 256 + 4*t);
    f32x4 a1lo = ld4(b1g + 4*t), a1hi = ld4(b1g + 256 + 4*t);
    f32x4 b2lo = ld4(b2g + 4*t), b2hi = ld4(b2g + 256 + 4*t);
    f32x4 zrv  = ld4(z + (bb << 8) + 4*t);
    f32x4 xo   = {0.f, 0.f, 0.f, 0.f};
    f32x4 w1cAlo, w1cAhi, w1cBlo, w1cBhi;     // w1 rows for units 510/511
    #pragma unroll
    for (int c = 0; c < 4; ++c) {
        const int kl = 4*t + c, kh = 256 + 4*t + c;
        w1cAlo[c] = w1[kl * HH + 510];
        w1cAhi[c] = w1[kh * HH + 510];
        w1cBlo[c] = ((kl % 255) >= 1) ? w1[kl * HH + 511] : 0.f;
        w1cBhi[c] = ((kh % 255) >= 1) ? w1[kh * HH + 511] : 0.f;
    }
    float ldacc = 0.f;

    const unsigned lbase = (unsigned)(unsigned long long)(lds_f*)&lds4[0];
    const unsigned va0 = lbase + 16u * (unsigned)t;
    const unsigned va1 = va0 + 10240u, va2 = va0 + 20480u, va3 = va0 + 30720u;

    // prologue: DMA sets 0..2 into slots 0..2 (step 0 refills slot 3 / set 3)
    __builtin_amdgcn_sched_barrier(0);
    #pragma unroll
    for (int s = 0; s < 3; ++s) {
        const float* gs = pk + (size_t)s * PKS + 4*t;
        float* ls = lds4 + s * 2560;
        #pragma unroll
        for (int j = 0; j < 10; ++j) gld16(gs + 256*j, ls + 256*j);
    }
    __builtin_amdgcn_sched_barrier(0);

    for (int g = 0; g < 32; ++g) {
        STEP(g, 0); STEP(g, 1); STEP(g, 2); STEP(g, 3);
        STEP(g, 4); STEP(g, 5); STEP(g, 6); STEP(g, 7);
    }

    // drain the tail DMAs still writing LDS, then store results
    asm volatile("s_waitcnt vmcnt(0)" ::: "memory");
    __builtin_amdgcn_sched_barrier(0);
    *(f32x4*)(out + (bb << 8) + 4*t) = xo;
    if (t == 0) out[BB * NN + bb] = -ldacc;
}

// ---------------- fallback (no workspace): verified round-1 kernel ----------
__global__ __launch_bounds__(256)
void made_seq_fb(const float* __restrict__ z,
                 const float* __restrict__ w0, const float* __restrict__ b0,
                 const float* __restrict__ w1, const float* __restrict__ b1,
                 const float* __restrict__ w2, const float* __restrict__ b2,
                 float* __restrict__ out) {
    const int bb = blockIdx.x;
    const int t  = threadIdx.x;
    const int u0 = t, u1 = t + 256;
    const int l0 = u0 % 255, s0 = u0 / 255;
    const int l1 = u1 % 255, s1 = u1 / 255;
    const int wave = t >> 6, lane = t & 63;

    __shared__ float red[2][4][2];
    __shared__ float pub[2][3][2];

    float a0_0 = b0[u0], a0_1 = b0[u1];
    float a1_0 = b1[u0], a1_1 = b1[u1];
    float ld = 0.f;

    for (int i = 0; i < NN; ++i) {
        float cw2m0 = (l0 < i) ? w2[i * HH + u0] : 0.f;
        float cw2a0 = (l0 < i) ? w2[(NN + i) * HH + u0] : 0.f;
        float cw2m1 = (l1 < i) ? w2[i * HH + u1] : 0.f;
        float cw2a1 = (l1 < i) ? w2[(NN + i) * HH + u1] : 0.f;
        float cw00  = (l0 >= i) ? w0[u0 * NN + i] : 0.f;
        float cw01  = (l1 >= i) ? w0[u1 * NN + i] : 0.f;
        bool g0 = (l0 >= (i % 255)), g1 = (l1 >= (i % 255));
        float w1a0 = g0 ? w1[u0 * HH + i] : 0.f;
        float w1a1 = g1 ? w1[u1 * HH + i] : 0.f;
        float w1b0 = g0 ? w1[u0 * HH + i + 255] : 0.f;
        float w1b1 = g1 ? w1[u1 * HH + i + 255] : 0.f;

        float h10 = fmaxf(a1_0, 0.f), h11 = fmaxf(a1_1, 0.f);
        float pm = h10 * cw2m0 + h11 * cw2m1;
        float pa = h10 * cw2a0 + h11 * cw2a1;
        #pragma unroll
        for (int offs = 32; offs > 0; offs >>= 1) {
            pm += __shfl_xor(pm, offs);
            pa += __shfl_xor(pa, offs);
        }
        const int bf = i & 1;
        if (lane == 0) { red[bf][wave][0] = pm; red[bf][wave][1] = pa; }
        if (l0 == i) { pub[bf][s0][0] = a0_0; pub[bf][s0][1] = cw00; }
        if (l1 == i) { pub[bf][s1][0] = a0_1; pub[bf][s1][1] = cw01; }
        __syncthreads();

        float mu = b2[i]      + red[bf][0][0] + red[bf][1][0] + red[bf][2][0] + red[bf][3][0];
        float al = b2[NN + i] + red[bf][0][1] + red[bf][1][1] + red[bf][2][1] + red[bf][3][1];
        ld += al;
        float xi = fmaf(z[bb * NN + i], __expf(al), mu);
        if (t == 0) out[bb * NN + i] = xi;

        a0_0 = fmaf(xi, cw00, a0_0);
        a0_1 = fmaf(xi, cw01, a0_1);

        float h0a = fmaxf(fmaf(xi, pub[bf][0][1], pub[bf][0][0]), 0.f);
        float h0b = fmaxf(fmaf(xi, pub[bf][1][1], pub[bf][1][0]), 0.f);
        a1_0 = fmaf(h0a, w1a0, a1_0);
        a1_1 = fmaf(h0a, w1a1, a1_1);
        a1_0 = fmaf(h0b, w1b0, a1_0);
        a1_1 = fmaf(h0b, w1b1, a1_1);
        if (i < 2) {
            float w1c0 = (l0 >= i) ? w1[u0 * HH + i + 510] : 0.f;
            float w1c1 = (l1 >= i) ? w1[u1 * HH + i + 510] : 0.f;
            float h0c = fmaxf(fmaf(xi, pub[bf][2][1], pub[bf][2][0]), 0.f);
            a1_0 = fmaf(h0c, w1c0, a1_0);
            a1_1 = fmaf(h0c, w1c1, a1_1);
        }
        __syncthreads();
    }

    if (t == 0) out[BB * NN + bb] = -ld;
}

extern "C" void kernel_launch(void* const* d_in, const int* in_sizes, int n_in,
                              void* d_out, int out_size, void* d_ws, size_t ws_size,
                              hipStream_t stream) {
    const float* z  = (const float*)d_in[0];
    const float* w0 = (const float*)d_in[1];
    const float* b0 = (const float*)d_in[2];
    const float* w1 = (const float*)d_in[3];
    const float* b1 = (const float*)d_in[4];
    const float* w2 = (const float*)d_in[5];
    const float* b2 = (const float*)d_in[6];
    float* out = (float*)d_out;

    const size_t need = (size_t)NN * PKS * sizeof(float);   // 2,621,440 B
    if (ws_size >= need) {
        float* pk = (float*)d_ws;
        made_prep<<<NN, 512, 0, stream>>>(w0, w1, w2, pk);
        made_seq64<<<BB, 64, 0, stream>>>(z, b0, b1, b2, w1, pk, out);
    } else {
        made_seq_fb<<<BB, 256, 0, stream>>>(z, w0, b0, w1, b1, w2, b2, out);
    }
}

// Round 9
// 83.791 us; speedup vs baseline: 1.9879x; 1.9879x over previous
//
#include <hip/hip_runtime.h>

#define NN 256
#define HH 512
#define BB 128
#define PKS (5 * HH)   // floats per packed step row-set (w2m, w2a, w0, w1a, w1b)

typedef float f32x4 __attribute__((ext_vector_type(4)));

// ---------------- prep: packed masked/transposed rows, one row-set per step -
// pk[i][0][k] = (k%255 <  i)           ? w2[i][k]     (mu row)
// pk[i][1][k] = (k%255 <  i)           ? w2[256+i][k] (alpha row)
// pk[i][2][k] = (k%255 >= i)           ? w0[k][i]     (w0 column i)
// pk[i][3][k] = (k%255 >= i%255)       ? w1[k][i]     (w1 column i)
// pk[i][4][k] = (k%255 >= (i+255)%255) ? w1[k][i+255]
__global__ __launch_bounds__(512)
void made_prep(const float* __restrict__ w0,
               const float* __restrict__ w1,
               const float* __restrict__ w2,
               float* __restrict__ pk) {
    const int i = blockIdx.x;     // step 0..255
    const int k = threadIdx.x;    // unit 0..511
    const int lev = k % 255;
    float* row = pk + (size_t)i * PKS;
    row[k]          = (lev < i)  ? w2[i * HH + k]        : 0.f;
    row[HH + k]     = (lev < i)  ? w2[(NN + i) * HH + k] : 0.f;
    row[2*HH + k]   = (lev >= i) ? w0[k * NN + i]        : 0.f;
    const int l1 = i % 255;
    row[3*HH + k]   = (lev >= l1) ? w1[k * HH + i]       : 0.f;
    const int j2 = i + 255;
    const int l2 = j2 % 255;
    row[4*HH + k]   = (lev >= l2) ? w1[k * HH + j2]      : 0.f;
}

// ---------------- single-wave sequential kernel -----------------------------
struct B10 { f32x4 q0,q1,q2,q3,q4,q5,q6,q7,q8,q9; };

__device__ __forceinline__ float rl_f(float v, int lane) {
    return __int_as_float(__builtin_amdgcn_readlane(__float_as_int(v), lane));
}

__device__ __forceinline__ f32x4 ld4(const float* p) { return *(const f32x4*)p; }

// pick element s (compile-time after inlining) of the 8 w0 values in q4/q5
__device__ __forceinline__ float q45c(const B10& b, int s) {
    switch (s) {
        case 0: return b.q4[0]; case 1: return b.q4[1];
        case 2: return b.q4[2]; case 3: return b.q4[3];
        case 4: return b.q5[0]; case 5: return b.q5[1];
        case 6: return b.q5[2]; default: return b.q5[3];
    }
}

#define DPP_ADD(v, ctrl, rm) \
    ((v) + __int_as_float(__builtin_amdgcn_update_dpp(0, __float_as_int(v), (ctrl), (rm), 0xf, false)))

// full-wave (64-lane) sum of pm and pa; totals end up in lane 63
__device__ __forceinline__ void reduce2(float& pm, float& pa) {
    pm = DPP_ADD(pm, 0x111, 0xf);  pa = DPP_ADD(pa, 0x111, 0xf);  // row_shr:1
    pm = DPP_ADD(pm, 0x112, 0xf);  pa = DPP_ADD(pa, 0x112, 0xf);  // row_shr:2
    pm = DPP_ADD(pm, 0x114, 0xf);  pa = DPP_ADD(pa, 0x114, 0xf);  // row_shr:4
    pm = DPP_ADD(pm, 0x118, 0xf);  pa = DPP_ADD(pa, 0x118, 0xf);  // row_shr:8
    pm = DPP_ADD(pm, 0x142, 0xa);  pa = DPP_ADD(pa, 0x142, 0xa);  // row_bcast15
    pm = DPP_ADD(pm, 0x143, 0xc);  pa = DPP_ADD(pa, 0x143, 0xc);  // row_bcast31
}

#define DOT8(res, A, B)  do {                                   \
    float t01_ = fmaf(h_[1], (A)[1], h_[0] * (A)[0]);           \
    float t23_ = fmaf(h_[3], (A)[3], h_[2] * (A)[2]);           \
    float t45_ = fmaf(h_[5], (B)[1], h_[4] * (B)[0]);           \
    float t67_ = fmaf(h_[7], (B)[3], h_[6] * (B)[2]);           \
    res = (t01_ + t23_) + (t45_ + t67_);                        \
} while (0)

// One autoregressive step (round-3-verified algebra). r is a literal 0..7;
// BUF = buffer (i & 3), loaded 4 steps ago by plain C++ loads. ALL 10
// refill loads (for step i+4) sit at the END of the step, pinned by
// sched_barrier(0): the scheduler cannot sink them toward their uses, and
// the backend's waitcnt pass emits correctly COUNTED vmcnt(N) at the use
// sites automatically. No inline-asm loads anywhere -> no liveness hazards.
#define STEP(g, r, BUF) do {                                                 \
    const int i_ = ((g) << 3) | (r);                                         \
    float h_[8];                                                             \
    h_[0] = fmaxf(a1v[0], 0.f); h_[1] = fmaxf(a1v[1], 0.f);                  \
    h_[2] = fmaxf(a1v[2], 0.f); h_[3] = fmaxf(a1v[3], 0.f);                  \
    h_[4] = fmaxf(a1v[4], 0.f); h_[5] = fmaxf(a1v[5], 0.f);                  \
    h_[6] = fmaxf(a1v[6], 0.f); h_[7] = fmaxf(a1v[7], 0.f);                  \
    float pm_, pa_;                                                          \
    DOT8(pa_, BUF.q2, BUF.q3);                                               \
    DOT8(pm_, BUF.q0, BUF.q1);                                               \
    reduce2(pm_, pa_);                                                       \
    const int sB_ = ((r) + 7) & 7;                                           \
    const int LB_ = ((r) == 0) ? ((g) + 31) : ((g) + 32);                    \
    const int zl_ = ((g) << 1) + ((r) >> 2);                                 \
    float a0A_ = rl_f(a0v[(r)], (g));                                        \
    float w0A_ = rl_f(q45c(BUF, (r)), (g));                                  \
    float a0B_ = rl_f(a0v[sB_], LB_);                                        \
    float w0B_ = rl_f(q45c(BUF, sB_), LB_);                                  \
    float ta_ = rl_f(pa_, 63), tm_ = rl_f(pm_, 63);                          \
    float al_ = ta_ + rl_f(b2v[(r)], (g) + 32);                              \
    float mu_ = tm_ + rl_f(b2v[(r)], (g));                                   \
    ldacc += al_;                                                            \
    float zi_ = rl_f(zrv[(r) & 3], zl_);                                     \
    float xi_ = fmaf(zi_, __expf(al_), mu_);                                 \
    xo[(r) & 3] = (t == zl_) ? xi_ : xo[(r) & 3];                            \
    float h0a_ = fmaxf(fmaf(xi_, w0A_, a0A_), 0.f);                          \
    float h0b_ = fmaxf(fmaf(xi_, w0B_, a0B_), 0.f);                          \
    if ((r) < 2 && (g) == 0) {  /* units 510/511 finalize at i=0,1 */        \
        float a0C_ = rl_f(a0v[6 + (r)], 63);                                 \
        float w0C_ = rl_f(q45c(BUF, 6 + (r)), 63);                           \
        float h0c_ = fmaxf(fmaf(xi_, w0C_, a0C_), 0.f);                      \
        const float* wc_ = ((r) == 0) ? w1c0v : w1c1v;                       \
        a1v[0] = fmaf(h0c_, wc_[0], a1v[0]); a1v[1] = fmaf(h0c_, wc_[1], a1v[1]); \
        a1v[2] = fmaf(h0c_, wc_[2], a1v[2]); a1v[3] = fmaf(h0c_, wc_[3], a1v[3]); \
        a1v[4] = fmaf(h0c_, wc_[4], a1v[4]); a1v[5] = fmaf(h0c_, wc_[5], a1v[5]); \
        a1v[6] = fmaf(h0c_, wc_[6], a1v[6]); a1v[7] = fmaf(h0c_, wc_[7], a1v[7]); \
    }                                                                        \
    a0v[0] = fmaf(xi_, BUF.q4[0], a0v[0]); a0v[1] = fmaf(xi_, BUF.q4[1], a0v[1]); \
    a0v[2] = fmaf(xi_, BUF.q4[2], a0v[2]); a0v[3] = fmaf(xi_, BUF.q4[3], a0v[3]); \
    a0v[4] = fmaf(xi_, BUF.q5[0], a0v[4]); a0v[5] = fmaf(xi_, BUF.q5[1], a0v[5]); \
    a0v[6] = fmaf(xi_, BUF.q5[2], a0v[6]); a0v[7] = fmaf(xi_, BUF.q5[3], a0v[7]); \
    a1v[0] = fmaf(h0b_, BUF.q8[0], fmaf(h0a_, BUF.q6[0], a1v[0]));           \
    a1v[1] = fmaf(h0b_, BUF.q8[1], fmaf(h0a_, BUF.q6[1], a1v[1]));           \
    a1v[2] = fmaf(h0b_, BUF.q8[2], fmaf(h0a_, BUF.q6[2], a1v[2]));           \
    a1v[3] = fmaf(h0b_, BUF.q8[3], fmaf(h0a_, BUF.q6[3], a1v[3]));           \
    a1v[4] = fmaf(h0b_, BUF.q9[0], fmaf(h0a_, BUF.q7[0], a1v[4]));           \
    a1v[5] = fmaf(h0b_, BUF.q9[1], fmaf(h0a_, BUF.q7[1], a1v[5]));           \
    a1v[6] = fmaf(h0b_, BUF.q9[2], fmaf(h0a_, BUF.q7[2], a1v[6]));           \
    a1v[7] = fmaf(h0b_, BUF.q9[3], fmaf(h0a_, BUF.q7[3], a1v[7]));           \
    /* ---- refill BUF with step i+4 (plain loads), pinned here ---- */      \
    {                                                                        \
        const float* pf_ = pk + (size_t)((i_ + 4) & 255) * PKS + o8;         \
        BUF.q0 = ld4(pf_);          BUF.q1 = ld4(pf_ + 4);                   \
        BUF.q2 = ld4(pf_ + HH);     BUF.q3 = ld4(pf_ + HH + 4);              \
        BUF.q4 = ld4(pf_ + 2*HH);   BUF.q5 = ld4(pf_ + 2*HH + 4);            \
        BUF.q6 = ld4(pf_ + 3*HH);   BUF.q7 = ld4(pf_ + 3*HH + 4);            \
        BUF.q8 = ld4(pf_ + 4*HH);   BUF.q9 = ld4(pf_ + 4*HH + 4);            \
    }                                                                        \
    __builtin_amdgcn_sched_barrier(0);                                       \
} while (0)

// One 64-thread wave per batch element. Lane t owns units 8t..8t+7.
// Distance-4 software pipeline with compiler-managed loads + counted waits;
// sched_barrier(0) per step only pins ISSUE order.
__global__ __launch_bounds__(64, 1)
void made_seq64(const float* __restrict__ z,
                const float* __restrict__ b0g,
                const float* __restrict__ b1g,
                const float* __restrict__ b2g,
                const float* __restrict__ w1,
                const float* __restrict__ pk,
                float* __restrict__ out) {
    const int bb = blockIdx.x;
    const int t  = threadIdx.x;
    const int o8 = t << 3;

    float a0v[8], a1v[8], b2v[8];
    {
        f32x4 a = ld4(b0g + o8), b = ld4(b0g + o8 + 4);
        a0v[0]=a[0]; a0v[1]=a[1]; a0v[2]=a[2]; a0v[3]=a[3];
        a0v[4]=b[0]; a0v[5]=b[1]; a0v[6]=b[2]; a0v[7]=b[3];
        a = ld4(b1g + o8); b = ld4(b1g + o8 + 4);
        a1v[0]=a[0]; a1v[1]=a[1]; a1v[2]=a[2]; a1v[3]=a[3];
        a1v[4]=b[0]; a1v[5]=b[1]; a1v[6]=b[2]; a1v[7]=b[3];
        a = ld4(b2g + o8); b = ld4(b2g + o8 + 4);
        b2v[0]=a[0]; b2v[1]=a[1]; b2v[2]=a[2]; b2v[3]=a[3];
        b2v[4]=b[0]; b2v[5]=b[1]; b2v[6]=b[2]; b2v[7]=b[3];
    }
    float w1c0v[8], w1c1v[8];           // w1 rows for units 510, 511
    #pragma unroll
    for (int j = 0; j < 8; ++j) {
        const int k = o8 + j;
        w1c0v[j] = w1[k * HH + 510];
        w1c1v[j] = ((k % 255) >= 1) ? w1[k * HH + 511] : 0.f;
    }
    f32x4 z4 = ld4(z + (bb << 8) + (t << 2));
    float zrv[4] = {z4[0], z4[1], z4[2], z4[3]};
    float xo[4]  = {0.f, 0.f, 0.f, 0.f};
    float ldacc  = 0.f;

    // prologue: fill the 4 pipeline buffers (sets 0..3), pin issue position
    B10 Ba, Bb, Bc, Bd;
    {
        const float* p0 = pk + o8;
        Ba.q0 = ld4(p0);        Ba.q1 = ld4(p0 + 4);
        Ba.q2 = ld4(p0 + HH);   Ba.q3 = ld4(p0 + HH + 4);
        Ba.q4 = ld4(p0 + 2*HH); Ba.q5 = ld4(p0 + 2*HH + 4);
        Ba.q6 = ld4(p0 + 3*HH); Ba.q7 = ld4(p0 + 3*HH + 4);
        Ba.q8 = ld4(p0 + 4*HH); Ba.q9 = ld4(p0 + 4*HH + 4);
        const float* p1 = pk + PKS + o8;
        Bb.q0 = ld4(p1);        Bb.q1 = ld4(p1 + 4);
        Bb.q2 = ld4(p1 + HH);   Bb.q3 = ld4(p1 + HH + 4);
        Bb.q4 = ld4(p1 + 2*HH); Bb.q5 = ld4(p1 + 2*HH + 4);
        Bb.q6 = ld4(p1 + 3*HH); Bb.q7 = ld4(p1 + 3*HH + 4);
        Bb.q8 = ld4(p1 + 4*HH); Bb.q9 = ld4(p1 + 4*HH + 4);
        const float* p2 = pk + 2*PKS + o8;
        Bc.q0 = ld4(p2);        Bc.q1 = ld4(p2 + 4);
        Bc.q2 = ld4(p2 + HH);   Bc.q3 = ld4(p2 + HH + 4);
        Bc.q4 = ld4(p2 + 2*HH); Bc.q5 = ld4(p2 + 2*HH + 4);
        Bc.q6 = ld4(p2 + 3*HH); Bc.q7 = ld4(p2 + 3*HH + 4);
        Bc.q8 = ld4(p2 + 4*HH); Bc.q9 = ld4(p2 + 4*HH + 4);
        const float* p3 = pk + 3*PKS + o8;
        Bd.q0 = ld4(p3);        Bd.q1 = ld4(p3 + 4);
        Bd.q2 = ld4(p3 + HH);   Bd.q3 = ld4(p3 + HH + 4);
        Bd.q4 = ld4(p3 + 2*HH); Bd.q5 = ld4(p3 + 2*HH + 4);
        Bd.q6 = ld4(p3 + 3*HH); Bd.q7 = ld4(p3 + 3*HH + 4);
        Bd.q8 = ld4(p3 + 4*HH); Bd.q9 = ld4(p3 + 4*HH + 4);
    }
    __builtin_amdgcn_sched_barrier(0);

    for (int g = 0; g < 32; ++g) {
        STEP(g, 0, Ba); STEP(g, 1, Bb); STEP(g, 2, Bc); STEP(g, 3, Bd);
        STEP(g, 4, Ba); STEP(g, 5, Bb); STEP(g, 6, Bc); STEP(g, 7, Bd);
    }

    *(f32x4*)(out + (bb << 8) + (t << 2)) = (f32x4){xo[0], xo[1], xo[2], xo[3]};
    if (t == 0) out[BB * NN + bb] = -ldacc;
}

// ---------------- fallback (no workspace): verified round-1 kernel ----------
__global__ __launch_bounds__(256)
void made_seq_fb(const float* __restrict__ z,
                 const float* __restrict__ w0, const float* __restrict__ b0,
                 const float* __restrict__ w1, const float* __restrict__ b1,
                 const float* __restrict__ w2, const float* __restrict__ b2,
                 float* __restrict__ out) {
    const int bb = blockIdx.x;
    const int t  = threadIdx.x;
    const int u0 = t, u1 = t + 256;
    const int l0 = u0 % 255, s0 = u0 / 255;
    const int l1 = u1 % 255, s1 = u1 / 255;
    const int wave = t >> 6, lane = t & 63;

    __shared__ float red[2][4][2];
    __shared__ float pub[2][3][2];

    float a0_0 = b0[u0], a0_1 = b0[u1];
    float a1_0 = b1[u0], a1_1 = b1[u1];
    float ld = 0.f;

    for (int i = 0; i < NN; ++i) {
        float cw2m0 = (l0 < i) ? w2[i * HH + u0] : 0.f;
        float cw2a0 = (l0 < i) ? w2[(NN + i) * HH + u0] : 0.f;
        float cw2m1 = (l1 < i) ? w2[i * HH + u1] : 0.f;
        float cw2a1 = (l1 < i) ? w2[(NN + i) * HH + u1] : 0.f;
        float cw00  = (l0 >= i) ? w0[u0 * NN + i] : 0.f;
        float cw01  = (l1 >= i) ? w0[u1 * NN + i] : 0.f;
        bool g0 = (l0 >= (i % 255)), g1 = (l1 >= (i % 255));
        float w1a0 = g0 ? w1[u0 * HH + i] : 0.f;
        float w1a1 = g1 ? w1[u1 * HH + i] : 0.f;
        float w1b0 = g0 ? w1[u0 * HH + i + 255] : 0.f;
        float w1b1 = g1 ? w1[u1 * HH + i + 255] : 0.f;

        float h10 = fmaxf(a1_0, 0.f), h11 = fmaxf(a1_1, 0.f);
        float pm = h10 * cw2m0 + h11 * cw2m1;
        float pa = h10 * cw2a0 + h11 * cw2a1;
        #pragma unroll
        for (int offs = 32; offs > 0; offs >>= 1) {
            pm += __shfl_xor(pm, offs);
            pa += __shfl_xor(pa, offs);
        }
        const int bf = i & 1;
        if (lane == 0) { red[bf][wave][0] = pm; red[bf][wave][1] = pa; }
        if (l0 == i) { pub[bf][s0][0] = a0_0; pub[bf][s0][1] = cw00; }
        if (l1 == i) { pub[bf][s1][0] = a0_1; pub[bf][s1][1] = cw01; }
        __syncthreads();

        float mu = b2[i]      + red[bf][0][0] + red[bf][1][0] + red[bf][2][0] + red[bf][3][0];
        float al = b2[NN + i] + red[bf][0][1] + red[bf][1][1] + red[bf][2][1] + red[bf][3][1];
        ld += al;
        float xi = fmaf(z[bb * NN + i], __expf(al), mu);
        if (t == 0) out[bb * NN + i] = xi;

        a0_0 = fmaf(xi, cw00, a0_0);
        a0_1 = fmaf(xi, cw01, a0_1);

        float h0a = fmaxf(fmaf(xi, pub[bf][0][1], pub[bf][0][0]), 0.f);
        float h0b = fmaxf(fmaf(xi, pub[bf][1][1], pub[bf][1][0]), 0.f);
        a1_0 = fmaf(h0a, w1a0, a1_0);
        a1_1 = fmaf(h0a, w1a1, a1_1);
        a1_0 = fmaf(h0b, w1b0, a1_0);
        a1_1 = fmaf(h0b, w1b1, a1_1);
        if (i < 2) {
            float w1c0 = (l0 >= i) ? w1[u0 * HH + i + 510] : 0.f;
            float w1c1 = (l1 >= i) ? w1[u1 * HH + i + 510] : 0.f;
            float h0c = fmaxf(fmaf(xi, pub[bf][2][1], pub[bf][2][0]), 0.f);
            a1_0 = fmaf(h0c, w1c0, a1_0);
            a1_1 = fmaf(h0c, w1c1, a1_1);
        }
        __syncthreads();
    }

    if (t == 0) out[BB * NN + bb] = -ld;
}

extern "C" void kernel_launch(void* const* d_in, const int* in_sizes, int n_in,
                              void* d_out, int out_size, void* d_ws, size_t ws_size,
                              hipStream_t stream) {
    const float* z  = (const float*)d_in[0];
    const float* w0 = (const float*)d_in[1];
    const float* b0 = (const float*)d_in[2];
    const float* w1 = (const float*)d_in[3];
    const float* b1 = (const float*)d_in[4];
    const float* w2 = (const float*)d_in[5];
    const float* b2 = (const float*)d_in[6];
    float* out = (float*)d_out;

    const size_t need = (size_t)NN * PKS * sizeof(float);   // 2,621,440 B
    if (ws_size >= need) {
        float* pk = (float*)d_ws;
        made_prep<<<NN, 512, 0, stream>>>(w0, w1, w2, pk);
        made_seq64<<<BB, 64, 0, stream>>>(z, b0, b1, b2, w1, pk, out);
    } else {
        made_seq_fb<<<BB, 256, 0, stream>>>(z, w0, b0, w1, b1, w2, b2, out);
    }
}